// Round 8
// baseline (1494.986 us; speedup 1.0000x reference)
//
#include <hip/hip_runtime.h>

typedef __attribute__((ext_vector_type(8))) _Float16 f16x8;
typedef __attribute__((ext_vector_type(16))) float f32x16;

#define B_    8
#define LSEQ  2048
#define DIM   1024
#define QBLK  64
#define NKB   4          // KBLK = 512

// ws images (pre-swizzled LDS byte-images, fp16):
//  Kimg: [m][b][dc 32][row 2048][32d]  (64B rows, slot swz: s^=(row>>1)&3)
//  Vimg: [m][b][kb4][kq4][band8][128d][128k] (256B rows, slot swz: s^=d&7)
#define KSEG_US ((size_t)32 * 2048 * 32)     // 4MB per (m,b)
#define VSEG_US ((size_t)128 * 16384)        // 4MB per (m,b)
#define WS_NEED ((size_t)(16 * KSEG_US + 16 * VSEG_US) * 2)   // 128 MiB

static __device__ __forceinline__ unsigned pk2(float a, float b) {
    return __builtin_bit_cast(unsigned, __builtin_amdgcn_cvt_pkrtz(a, b));
}
static __device__ __forceinline__ f32x16 mm(f16x8 a, f16x8 b, f32x16 c) {
    return __builtin_amdgcn_mfma_f32_32x32x16_f16(a, b, c, 0, 0, 0);
}
#define VMCNT(n) asm volatile("s_waitcnt vmcnt(" #n ")" ::: "memory")
#define LGKM0()  asm volatile("s_waitcnt lgkmcnt(0)" ::: "memory")
#define BAR()    do { asm volatile("" ::: "memory"); __builtin_amdgcn_s_barrier(); \
                      asm volatile("" ::: "memory"); } while (0)
static __device__ __forceinline__ int s3(int x) { return x >= 3 ? x - 3 : x; }

static __device__ __forceinline__ void gll16(const void* g, void* l) {
    __builtin_amdgcn_global_load_lds(
        (const __attribute__((address_space(1))) void*)g,
        (__attribute__((address_space(3))) void*)l, 16, 0, 0);
}

// ============ prepass: fp32 -> pre-swizzled fragment-ready fp16 images ============
__global__ __launch_bounds__(256)
void prepass(const float* __restrict__ Sp, const float* __restrict__ Dp,
             unsigned short* __restrict__ Kimg, unsigned short* __restrict__ Vimg)
{
    const int blk  = blockIdx.x;           // 2048 = m2 * b8 * kt16 * band8
    const int band = blk & 7;
    const int kt   = (blk >> 3) & 15;
    const int b    = (blk >> 7) & 7;
    const int m    = blk >> 10;
    const float* src = (m ? Dp : Sp) + ((size_t)b * LSEQ + kt * 128) * DIM + band * 128;
    char* kseg = (char*)(Kimg + (size_t)(m * 8 + b) * KSEG_US);
    char* vit  = (char*)(Vimg + (size_t)(m * 8 + b) * VSEG_US + (size_t)(kt * 8 + band) * 16384);

    __shared__ float tile[128][132];
    const int t = threadIdx.x;

    #pragma unroll
    for (int i = 0; i < 16; ++i) {
        const int idx = t + i * 256;
        const int r = idx >> 5, c4 = (idx & 31) << 2;
        *(float4*)&tile[r][c4] = *(const float4*)(src + (size_t)r * DIM + c4);
    }
    __syncthreads();

    // KQ emit: 128 rows x 4 dc x 4 slots
    #pragma unroll
    for (int i = 0; i < 8; ++i) {
        const int idx = t + i * 256;
        const int r   = idx >> 4;
        const int rem = idx & 15;
        const int dcl = rem >> 2, sg = rem & 3;
        const int grow = kt * 128 + r;
        const float* sp = &tile[r][dcl * 32 + sg * 8];
        uint4 o;
        o.x = pk2(sp[0], sp[1]); o.y = pk2(sp[2], sp[3]);
        o.z = pk2(sp[4], sp[5]); o.w = pk2(sp[6], sp[7]);
        const size_t off = ((size_t)(band * 4 + dcl) * 2048 + grow) * 64
                         + (size_t)((sg ^ ((grow >> 1) & 3)) * 16);
        *(uint4*)(kseg + off) = o;
    }
    // V emit: item [128 d][128 k], pk2 pairs along k
    #pragma unroll
    for (int i = 0; i < 8; ++i) {
        const int idx = t + i * 256;
        const int d  = idx >> 4;
        const int sg = idx & 15;
        const int k0 = sg * 8;
        const int dcol = band * 128 - band * 128 + d;   // local col within tile = d
        uint4 o;
        o.x = pk2(tile[k0 + 0][dcol], tile[k0 + 1][dcol]);
        o.y = pk2(tile[k0 + 2][dcol], tile[k0 + 3][dcol]);
        o.z = pk2(tile[k0 + 4][dcol], tile[k0 + 5][dcol]);
        o.w = pk2(tile[k0 + 6][dcol], tile[k0 + 7][dcol]);
        const size_t off = (size_t)d * 256 + (size_t)((sg ^ (d & 7)) * 16);
        *(uint4*)(vit + off) = o;
    }
}

// ============ main: KBLK=512, 2x2 QK blocking, quarter-staged P, R4 protocol ============
__global__ __launch_bounds__(512, 2)
void coattn_main(const float* __restrict__ Sp, const float* __restrict__ Dp,
                 float* __restrict__ outp,
                 const unsigned short* __restrict__ Kimg,
                 const unsigned short* __restrict__ Vimg)
{
    const int s   = blockIdx.x;
    const int qb  = (s >> 3) & 31;
    const int dir = s >> 8;
    const int b   = s & 7;
    const int mat_k = dir, mat_q = 1 - dir;

    const float* Qg = (dir ? Sp : Dp) + (size_t)b * LSEQ * DIM;
    float* Og = outp + (size_t)dir * ((size_t)B_ * LSEQ * DIM) + (size_t)b * LSEQ * DIM;
    const int q0 = qb * QBLK;

    const char* kseg = (const char*)(Kimg + (size_t)(mat_k * 8 + b) * KSEG_US);
    const char* qseg = (const char*)(Kimg + (size_t)(mat_q * 8 + b) * KSEG_US);
    const char* vseg = (const char*)(Vimg + (size_t)(mat_k * 8 + b) * VSEG_US);

    __shared__ unsigned short Rr[3][16384];   // 96 KB (32KB slots, K-chunks / V-items)
    __shared__ unsigned short Qr[3][2048];    // 12 KB (4KB slots)
    __shared__ unsigned short Pq[8192];       // 16 KB [64q][128k] swizzled quarter-P
    __shared__ float redmax[2][8][32];
    __shared__ float redsum[2][8][32];
    __shared__ float alf[QBLK];

    const int t = threadIdx.x, lane = t & 63, w = t >> 6;
    const int l31 = lane & 31, hi = lane >> 5;
    const int dq = w & 3, qh = w >> 2;

    const int R0  = 64 * w + l31;          // k-local rows: tiles at R0, R0+32
    const int ksw = (l31 >> 1) & 3;        // shared K/Q slot swizzle
    const int dl  = dq * 32 + l31;         // PV d-col (local in 128-band)
    const int qq  = qh * 32 + l31;         // PV pa q-row

    f32x16 O[8];
    #pragma unroll
    for (int i = 0; i < 8; ++i)
        #pragma unroll
        for (int r = 0; r < 16; ++r) O[i][r] = 0.0f;

    f32x16 C00, C01, C10, C11;
    float m_run0 = -INFINITY, m_run1 = -INFINITY, l_run0 = 0.0f, l_run1 = 0.0f;

    // ---- DMA helpers (per-wave; K/V: 4 ops, Q: 1 op on waves 0-3) ----
    #define ISSUE_K(KB, DC, SL) do {                                              \
        const char* g_ = kseg + ((size_t)(DC) * 2048 + (size_t)(KB) * 512) * 64;  \
        char* l_ = (char*)Rr[SL];                                                 \
        _Pragma("unroll")                                                         \
        for (int j_ = 0; j_ < 4; ++j_) {                                          \
            const int o_ = (w * 4 + j_) * 1024;                                   \
            gll16(g_ + o_ + lane * 16, l_ + o_);                                  \
        } } while (0)
    #define ISSUE_Q(DC, SL) do {                                                  \
        if (w < 4) {                                                              \
            const char* g_ = qseg + ((size_t)(DC) * 2048 + (size_t)q0) * 64;      \
            char* l_ = (char*)Qr[SL];                                             \
            const int o_ = w * 1024;                                              \
            gll16(g_ + o_ + lane * 16, l_ + o_);                                  \
        } } while (0)
    #define ISSUE_V(KB, VI, SL) do {                                              \
        const char* g_ = vseg + ((size_t)((KB) * 32 + (VI))) * 32768;             \
        char* l_ = (char*)Rr[SL];                                                 \
        _Pragma("unroll")                                                         \
        for (int j_ = 0; j_ < 4; ++j_) {                                          \
            const int o_ = (w * 4 + j_) * 1024;                                   \
            gll16(g_ + o_ + lane * 16, l_ + o_);                                  \
        } } while (0)

    #define QK_MMA() do {                                                         \
        const char* Kb = (const char*)Rr[rs];                                     \
        const char* Qb = (const char*)Qr[qrs];                                    \
        f16x8 k00 = *(const f16x8*)(Kb + R0 * 64        + ((hi     ^ ksw) * 16)); \
        f16x8 k01 = *(const f16x8*)(Kb + R0 * 64        + (((2+hi) ^ ksw) * 16)); \
        f16x8 k10 = *(const f16x8*)(Kb + (R0 + 32) * 64 + ((hi     ^ ksw) * 16)); \
        f16x8 k11 = *(const f16x8*)(Kb + (R0 + 32) * 64 + (((2+hi) ^ ksw) * 16)); \
        f16x8 q00 = *(const f16x8*)(Qb + l31 * 64        + ((hi     ^ ksw) * 16));\
        f16x8 q01 = *(const f16x8*)(Qb + l31 * 64        + (((2+hi) ^ ksw) * 16));\
        f16x8 q10 = *(const f16x8*)(Qb + (l31 + 32) * 64 + ((hi     ^ ksw) * 16));\
        f16x8 q11 = *(const f16x8*)(Qb + (l31 + 32) * 64 + (((2+hi) ^ ksw) * 16));\
        __builtin_amdgcn_s_setprio(1);                                            \
        C00 = mm(k00, q00, C00); C01 = mm(k00, q10, C01);                         \
        C10 = mm(k10, q00, C10); C11 = mm(k10, q10, C11);                         \
        C00 = mm(k01, q01, C00); C01 = mm(k01, q11, C01);                         \
        C10 = mm(k11, q01, C10); C11 = mm(k11, q11, C11);                         \
        __builtin_amdgcn_s_setprio(0);                                            \
    } while (0)

    // prologue: KQ items 0,1 of kb 0
    ISSUE_K(0, 0, 0); ISSUE_Q(0, 0);
    ISSUE_K(0, 1, 1); ISSUE_Q(1, 1);
    int rs = 0, qrs = 0;

    #pragma unroll 1
    for (int kb = 0; kb < NKB; ++kb) {
        #pragma unroll
        for (int r = 0; r < 16; ++r) { C00[r] = 0.f; C01[r] = 0.f; C10[r] = 0.f; C11[r] = 0.f; }

        // ---- QK phases 0..31 ----
        #pragma unroll 1
        for (int dc = 0; dc < 30; ++dc) {
            BAR();
            ISSUE_K(kb, dc + 2, s3(rs + 2)); ISSUE_Q(dc + 2, s3(qrs + 2));
            if (w < 4) { VMCNT(10); } else { VMCNT(8); }
            QK_MMA();
            rs = s3(rs + 1); qrs = s3(qrs + 1);
        }
        BAR();                                   // dc = 30: start V prefetch
        ISSUE_V(kb, 0, s3(rs + 2));
        if (w < 4) { VMCNT(9); } else { VMCNT(8); }
        QK_MMA();
        rs = s3(rs + 1); qrs = s3(qrs + 1);
        BAR();                                   // dc = 31
        ISSUE_V(kb, 1, s3(rs + 2));
        VMCNT(8);
        QK_MMA();
        rs = s3(rs + 1); qrs = s3(qrs + 1);

        // ---- online softmax (lgkm-only barriers; V0,V1 DMA stays in flight) ----
        float rm0 = -INFINITY, rm1 = -INFINITY;
        #pragma unroll
        for (int r = 0; r < 16; ++r) {
            rm0 = fmaxf(rm0, fmaxf(C00[r], C10[r]));
            rm1 = fmaxf(rm1, fmaxf(C01[r], C11[r]));
        }
        rm0 = fmaxf(rm0, __shfl_xor(rm0, 32));
        rm1 = fmaxf(rm1, __shfl_xor(rm1, 32));
        if (lane < 32) { redmax[0][w][l31] = rm0; redmax[1][w][l31] = rm1; }
        LGKM0(); BAR();

        float bm0 = redmax[0][0][l31], bm1 = redmax[1][0][l31];
        #pragma unroll
        for (int j = 1; j < 8; ++j) {
            bm0 = fmaxf(bm0, redmax[0][j][l31]);
            bm1 = fmaxf(bm1, redmax[1][j][l31]);
        }
        const float mn0 = fmaxf(m_run0, bm0), mn1 = fmaxf(m_run1, bm1);
        const float al0 = __expf(m_run0 - mn0), al1 = __expf(m_run1 - mn1);
        float p00[16], p01[16], p10[16], p11[16];
        float ps0 = 0.f, ps1 = 0.f;
        #pragma unroll
        for (int r = 0; r < 16; ++r) {
            p00[r] = __expf(C00[r] - mn0); p10[r] = __expf(C10[r] - mn0);
            p01[r] = __expf(C01[r] - mn1); p11[r] = __expf(C11[r] - mn1);
            ps0 += p00[r] + p10[r];
            ps1 += p01[r] + p11[r];
        }
        ps0 += __shfl_xor(ps0, 32);
        ps1 += __shfl_xor(ps1, 32);
        if (lane < 32) {
            redsum[0][w][l31] = ps0; redsum[1][w][l31] = ps1;
            if (w == 0) { alf[l31] = al0; alf[32 + l31] = al1; }
        }
        // pack P to fp16 pairs (kept in regs until this wave's quarter)
        uint2 ph[16];
        #pragma unroll
        for (int g = 0; g < 4; ++g) {
            ph[0 * 4 + g] = make_uint2(pk2(p00[4*g], p00[4*g+1]), pk2(p00[4*g+2], p00[4*g+3]));
            ph[1 * 4 + g] = make_uint2(pk2(p01[4*g], p01[4*g+1]), pk2(p01[4*g+2], p01[4*g+3]));
            ph[2 * 4 + g] = make_uint2(pk2(p10[4*g], p10[4*g+1]), pk2(p10[4*g+2], p10[4*g+3]));
            ph[3 * 4 + g] = make_uint2(pk2(p11[4*g], p11[4*g+1]), pk2(p11[4*g+2], p11[4*g+3]));
        }
        LGKM0(); BAR();

        float bs0 = 0.f, bs1 = 0.f;
        #pragma unroll
        for (int j = 0; j < 8; ++j) { bs0 += redsum[0][j][l31]; bs1 += redsum[1][j][l31]; }
        l_run0 = l_run0 * al0 + bs0; m_run0 = mn0;
        l_run1 = l_run1 * al1 + bs1; m_run1 = mn1;

        float alr[16];
        #pragma unroll
        for (int r = 0; r < 16; ++r)
            alr[r] = alf[qh * 32 + (r & 3) + 8 * (r >> 2) + 4 * hi];
        #pragma unroll
        for (int i = 0; i < 8; ++i)
            #pragma unroll
            for (int r = 0; r < 16; ++r) O[i][r] *= alr[r];

        // ---- PV: 4 quarters x 8 bands ----
        #pragma unroll 1
        for (int kq = 0; kq < 4; ++kq) {
            if ((w >> 1) == kq) {   // stage this quarter's P from regs
                #pragma unroll
                for (int kt = 0; kt < 2; ++kt)
                    #pragma unroll
                    for (int qt = 0; qt < 2; ++qt)
                        #pragma unroll
                        for (int g = 0; g < 4; ++g) {
                            const int q  = qt * 32 + l31;
                            const int k0 = (w & 1) * 64 + kt * 32 + 8 * g + 4 * hi;
                            const int sg = k0 >> 3;
                            *(uint2*)((char*)Pq + q * 256 + ((sg ^ (q & 7)) * 16) + (k0 & 7) * 2)
                                = ph[(kt * 2 + qt) * 4 + g];
                        }
            }
            LGKM0(); BAR();
            f16x8 pa[8];
            #pragma unroll
            for (int kc = 0; kc < 8; ++kc)
                pa[kc] = *(const f16x8*)((char*)Pq + qq * 256 + (((2 * kc + hi) ^ (qq & 7)) * 16));

            #pragma unroll 1
            for (int band = 0; band < 8; ++band) {
                BAR();
                const int ip = kq * 8 + band;
                const int ni = ip + 2;
                if (ni < 32) {
                    ISSUE_V(kb, ni, s3(rs + 2));
                } else if (kb + 1 < NKB) {
                    ISSUE_K(kb + 1, ni - 32, s3(rs + 2));
                    ISSUE_Q(ni - 32, ni == 32 ? qrs : s3(qrs + 1));
                }
                if (ip < 30) { VMCNT(8); }
                else if (kb + 1 < NKB) {
                    if (ip == 30) { if (w < 4) { VMCNT(9); } else { VMCNT(8); } }
                    else          { if (w < 4) { VMCNT(10); } else { VMCNT(8); } }
                } else {
                    if (ip == 30) { VMCNT(4); } else { VMCNT(0); }
                }
                const char* Vb = (const char*)Rr[rs];
                __builtin_amdgcn_s_setprio(1);
                #pragma unroll
                for (int kc = 0; kc < 8; ++kc) {
                    f16x8 vb = *(const f16x8*)(Vb + dl * 256 + (((2 * kc + hi) ^ (dl & 7)) * 16));
                    O[band] = mm(pa[kc], vb, O[band]);
                }
                __builtin_amdgcn_s_setprio(0);
                rs = s3(rs + 1);
            }
        }
    }

    // ---- epilogue: out = residual(Q) + O / l ----
    __syncthreads();
    if (lane < 32 && w == 0) { alf[l31] = 1.0f / l_run0; alf[32 + l31] = 1.0f / l_run1; }
    __syncthreads();
    #pragma unroll
    for (int r = 0; r < 16; ++r) {
        const int qr = qh * 32 + (r & 3) + 8 * (r >> 2) + 4 * hi;
        const float il = alf[qr];
        const size_t rowoff = (size_t)(q0 + qr) * DIM;
        #pragma unroll
        for (int band = 0; band < 8; ++band) {
            const int dcol = band * 128 + dq * 32 + l31;
            Og[rowoff + dcol] = Qg[rowoff + dcol] + O[band][r] * il;
        }
    }
    #undef ISSUE_K
    #undef ISSUE_Q
    #undef ISSUE_V
    #undef QK_MMA
}

// ============ fallback (round-2 kernel, verbatim — used if ws too small) ============
#define KBLK_F 128
#define NKBF   16
#define NDC    8
#define NBAND  8

__global__ __launch_bounds__(512, 2)
void coattn_fb(const float* __restrict__ Sp, const float* __restrict__ Dp,
               float* __restrict__ outp)
{
    const int s   = blockIdx.x;
    const int g   = (s & 7) | ((s >> 8) << 3);
    const int qb  = (s >> 3) & 31;
    const int dir = g >> 3;
    const int b   = g & 7;

    const float* Qg = (dir ? Sp : Dp) + (size_t)b * LSEQ * DIM;
    const float* Kg = (dir ? Dp : Sp) + (size_t)b * LSEQ * DIM;
    float* Og = outp + (size_t)dir * ((size_t)B_ * LSEQ * DIM) + (size_t)b * LSEQ * DIM;
    const int q0 = qb * QBLK;

    __shared__ unsigned short Klds[KBLK_F * 128];
    __shared__ unsigned short Qlds[QBLK * 128];
    __shared__ unsigned short Plds[QBLK * KBLK_F];
    __shared__ unsigned short Vlds[128 * KBLK_F];
    __shared__ float redmax[2][4][32];
    __shared__ float redsum[2][4][32];
    __shared__ float alf[QBLK];

    const int t    = threadIdx.x;
    const int lane = t & 63;
    const int w    = t >> 6;
    const int l31  = lane & 31;
    const int hi   = lane >> 5;
    const int ksub = w & 3;
    const int qh   = w >> 2;

    f32x16 O[NBAND];
    #pragma unroll
    for (int i = 0; i < NBAND; ++i)
        #pragma unroll
        for (int r = 0; r < 16; ++r) O[i][r] = 0.0f;

    float m_run = -INFINITY, l_run = 0.0f;

    const int srow = t >> 4;
    const int fcol = (t & 15) << 2;
    const int vmm  = t & 31;
    const int vkp0 = t >> 5;

    const int krow = ksub * 32 + l31;
    const int qrow = qh * 32 + l31;

    for (int kb = 0; kb < NKBF; ++kb) {
        const int k0g = kb * KBLK_F;
        f32x16 C;
        #pragma unroll
        for (int r = 0; r < 16; ++r) C[r] = 0.0f;

        float4 kreg[8], qreg[4];
        #pragma unroll
        for (int pass = 0; pass < 4; ++pass)
            #pragma unroll
            for (int h = 0; h < 2; ++h)
                kreg[pass * 2 + h] = *(const float4*)(Kg + (size_t)(k0g + pass * 32 + srow) * DIM + fcol + h * 64);
        #pragma unroll
        for (int pass = 0; pass < 2; ++pass)
            #pragma unroll
            for (int h = 0; h < 2; ++h)
                qreg[pass * 2 + h] = *(const float4*)(Qg + (size_t)(q0 + pass * 32 + srow) * DIM + fcol + h * 64);

        #pragma unroll 1
        for (int dc = 0; dc < NDC; ++dc) {
            __syncthreads();
            #pragma unroll
            for (int pass = 0; pass < 4; ++pass)
                #pragma unroll
                for (int h = 0; h < 2; ++h) {
                    const int row = pass * 32 + srow;
                    const int d   = fcol + h * 64;
                    const float4 v = kreg[pass * 2 + h];
                    *(uint2*)&Klds[row * 128 + (d ^ ((row & 7) << 3))] =
                        make_uint2(pk2(v.x, v.y), pk2(v.z, v.w));
                }
            #pragma unroll
            for (int pass = 0; pass < 2; ++pass)
                #pragma unroll
                for (int h = 0; h < 2; ++h) {
                    const int row = pass * 32 + srow;
                    const int d   = fcol + h * 64;
                    const float4 v = qreg[pass * 2 + h];
                    *(uint2*)&Qlds[row * 128 + (d ^ ((row & 7) << 3))] =
                        make_uint2(pk2(v.x, v.y), pk2(v.z, v.w));
                }
            __syncthreads();
            if (dc + 1 < NDC) {
                const int dbase = (dc + 1) * 128;
                #pragma unroll
                for (int pass = 0; pass < 4; ++pass)
                    #pragma unroll
                    for (int h = 0; h < 2; ++h)
                        kreg[pass * 2 + h] = *(const float4*)(Kg + (size_t)(k0g + pass * 32 + srow) * DIM + dbase + fcol + h * 64);
                #pragma unroll
                for (int pass = 0; pass < 2; ++pass)
                    #pragma unroll
                    for (int h = 0; h < 2; ++h)
                        qreg[pass * 2 + h] = *(const float4*)(Qg + (size_t)(q0 + pass * 32 + srow) * DIM + dbase + fcol + h * 64);
            }
            #pragma unroll
            for (int kc = 0; kc < 8; ++kc) {
                const int d0 = kc * 16 + hi * 8;
                f16x8 a  = *(const f16x8*)&Klds[krow * 128 + (d0 ^ ((krow & 7) << 3))];
                f16x8 bq = *(const f16x8*)&Qlds[qrow * 128 + (d0 ^ ((qrow & 7) << 3))];
                C = __builtin_amdgcn_mfma_f32_32x32x16_f16(a, bq, C, 0, 0, 0);
            }
        }

        float rm = -INFINITY;
        #pragma unroll
        for (int r = 0; r < 16; ++r) rm = fmaxf(rm, C[r]);
        rm = fmaxf(rm, __shfl_xor(rm, 32));
        if (lane < 32) redmax[qh][ksub][l31] = rm;
        __syncthreads();

        const float bm = fmaxf(fmaxf(redmax[qh][0][l31], redmax[qh][1][l31]),
                               fmaxf(redmax[qh][2][l31], redmax[qh][3][l31]));
        const float mn = fmaxf(m_run, bm);
        const float al = __expf(m_run - mn);
        float p[16];
        float ps = 0.0f;
        #pragma unroll
        for (int r = 0; r < 16; ++r) { p[r] = __expf(C[r] - mn); ps += p[r]; }
        ps += __shfl_xor(ps, 32);
        if (lane < 32) {
            redsum[qh][ksub][l31] = ps;
            if (ksub == 0) alf[qh * 32 + l31] = al;
        }
        {
            #pragma unroll
            for (int rp = 0; rp < 8; ++rp) {
                const int r  = rp * 2;
                const int kk = ksub * 32 + (r & 3) + 8 * (r >> 2) + 4 * hi;
                *(unsigned*)&Plds[qrow * KBLK_F + (kk ^ ((qrow & 7) << 3))] = pk2(p[r], p[r + 1]);
            }
        }
        __syncthreads();

        const float bs = redsum[qh][0][l31] + redsum[qh][1][l31] +
                         redsum[qh][2][l31] + redsum[qh][3][l31];
        l_run = l_run * al + bs;
        m_run = mn;

        float alr[16];
        #pragma unroll
        for (int r = 0; r < 16; ++r)
            alr[r] = alf[qh * 32 + (r & 3) + 8 * (r >> 2) + 4 * hi];
        #pragma unroll
        for (int i = 0; i < NBAND; ++i)
            #pragma unroll
            for (int r = 0; r < 16; ++r) O[i][r] *= alr[r];

        f16x8 pa[8];
        #pragma unroll
        for (int kc = 0; kc < 8; ++kc) {
            const int kk0 = kc * 16 + hi * 8;
            pa[kc] = *(const f16x8*)&Plds[qrow * KBLK_F + (kk0 ^ ((qrow & 7) << 3))];
        }

        float4 v0s[4], v1s[4];
        #pragma unroll
        for (int pass = 0; pass < 4; ++pass) {
            const int kp = pass * 16 + vkp0;
            v0s[pass] = *(const float4*)(Kg + (size_t)(k0g + 2 * kp) * DIM + vmm * 4);
            v1s[pass] = *(const float4*)(Kg + (size_t)(k0g + 2 * kp + 1) * DIM + vmm * 4);
        }

        #pragma unroll
        for (int band = 0; band < NBAND; ++band) {
            __syncthreads();
            #pragma unroll
            for (int pass = 0; pass < 4; ++pass) {
                const int kp = pass * 16 + vkp0;
                const float* a0 = (const float*)&v0s[pass];
                const float* a1 = (const float*)&v1s[pass];
                #pragma unroll
                for (int j = 0; j < 4; ++j) {
                    const int dclw = vmm * 4 + j;
                    *(unsigned*)&Vlds[dclw * KBLK_F + ((2 * kp) ^ ((dclw & 7) << 3))] = pk2(a0[j], a1[j]);
                }
            }
            __syncthreads();
            if (band + 1 < NBAND) {
                const int cb = (band + 1) * 128;
                #pragma unroll
                for (int pass = 0; pass < 4; ++pass) {
                    const int kp = pass * 16 + vkp0;
                    v0s[pass] = *(const float4*)(Kg + (size_t)(k0g + 2 * kp) * DIM + cb + vmm * 4);
                    v1s[pass] = *(const float4*)(Kg + (size_t)(k0g + 2 * kp + 1) * DIM + cb + vmm * 4);
                }
            }
            const int dclr = ksub * 32 + l31;
            const int sw  = (dclr & 7) << 3;
            #pragma unroll
            for (int kc = 0; kc < 8; ++kc) {
                const int kk0 = kc * 16 + hi * 8;
                f16x8 vb = *(const f16x8*)&Vlds[dclr * KBLK_F + (kk0 ^ sw)];
                O[band] = __builtin_amdgcn_mfma_f32_32x32x16_f16(pa[kc], vb, O[band], 0, 0, 0);
            }
        }
    }

    if (lane < 32 && ksub == 0) alf[qh * 32 + l31] = 1.0f / l_run;
    __syncthreads();
    #pragma unroll
    for (int r = 0; r < 16; ++r) {
        const int qr = qh * 32 + (r & 3) + 8 * (r >> 2) + 4 * hi;
        const float il = alf[qr];
        const size_t rowoff = (size_t)(q0 + qr) * DIM;
        #pragma unroll
        for (int band = 0; band < NBAND; ++band) {
            const int dcol = band * 128 + ksub * 32 + l31;
            Og[rowoff + dcol] = Qg[rowoff + dcol] + O[band][r] * il;
        }
    }
}

extern "C" void kernel_launch(void* const* d_in, const int* in_sizes, int n_in,
                              void* d_out, int out_size, void* d_ws, size_t ws_size,
                              hipStream_t stream) {
    const float* S = (const float*)d_in[0];
    const float* D = (const float*)d_in[1];
    float* out = (float*)d_out;
    if (ws_size >= WS_NEED) {
        unsigned short* Kimg = (unsigned short*)d_ws;
        unsigned short* Vimg = Kimg + 16 * KSEG_US;
        prepass<<<dim3(2048, 1, 1), dim3(256, 1, 1), 0, stream>>>(S, D, Kimg, Vimg);
        coattn_main<<<dim3(512, 1, 1), dim3(512, 1, 1), 0, stream>>>(S, D, out, Kimg, Vimg);
    } else {
        coattn_fb<<<dim3(512, 1, 1), dim3(512, 1, 1), 0, stream>>>(S, D, out);
    }
}

// Round 9
// 829.745 us; speedup vs baseline: 1.8017x; 1.8017x over previous
//
#include <hip/hip_runtime.h>

typedef __attribute__((ext_vector_type(8))) _Float16 f16x8;
typedef __attribute__((ext_vector_type(16))) float f32x16;

#define B_    8
#define LSEQ  2048
#define DIM   1024
#define QBLK  64
#define KBLK  128
#define NKB   (LSEQ / KBLK)   // 16
#define NBAND 8

// K/V image geometry: 32KB tiles (128x128 fp16, 4-bit row-XOR swizzle baked in)
#define TILE_US   16384        // ushorts per tile
#define KIMG_US   ((size_t)2 * 8 * 16 * 8 * TILE_US)   // 64 MB
#define WS_NEED   ((size_t)2 * KIMG_US * 2)            // 128 MB

static __device__ __forceinline__ unsigned pk2(float a, float b) {
    return __builtin_bit_cast(unsigned, __builtin_amdgcn_cvt_pkrtz(a, b));
}

#define VMCNT(n) asm volatile("s_waitcnt vmcnt(" #n ")" ::: "memory")
#define LGKM0()  asm volatile("s_waitcnt lgkmcnt(0)" ::: "memory")
#define BAR()    do { asm volatile("" ::: "memory"); __builtin_amdgcn_s_barrier(); \
                      asm volatile("" ::: "memory"); } while (0)

static __device__ __forceinline__ int s3(int x) { return x >= 3 ? x - 3 : x; }

static __device__ __forceinline__ void gll16(const void* g, void* l) {
    __builtin_amdgcn_global_load_lds(
        (const __attribute__((address_space(1))) void*)g,
        (__attribute__((address_space(3))) void*)l, 16, 0, 0);
}

// 32KB tile: 8 waves x 4 ops x 1KB ; 16KB tile: 8 waves x 2 ops x 1KB
static __device__ __forceinline__ void issue32(const unsigned short* gt, unsigned short* lb, int w, int lane) {
    #pragma unroll
    for (int j = 0; j < 4; ++j) {
        const int off = (w * 4 + j) * 1024;
        gll16((const char*)gt + off + lane * 16, (char*)lb + off);
    }
}
static __device__ __forceinline__ void issue16(const unsigned short* gt, unsigned short* lb, int w, int lane) {
    #pragma unroll
    for (int j = 0; j < 2; ++j) {
        const int off = (w * 2 + j) * 1024;
        gll16((const char*)gt + off + lane * 16, (char*)lb + off);
    }
}

// ============ prepass: fp32 -> fp16 images, 4-bit row-XOR swizzle ============
__global__ __launch_bounds__(256)
void prepass(const float* __restrict__ Sp, const float* __restrict__ Dp,
             unsigned short* __restrict__ Kimg, unsigned short* __restrict__ Vimg)
{
    const int blk = blockIdx.x;            // 2*8*16*8 = 2048
    const int dc = blk & 7;
    const int kb = (blk >> 3) & 15;
    const int b  = (blk >> 7) & 7;
    const int m  = blk >> 10;
    const float* src = (m ? Dp : Sp) + ((size_t)b * LSEQ + kb * 128) * DIM + dc * 128;
    unsigned short* kt = Kimg + (size_t)((((m * 8 + b) * 16 + kb) * 8) + dc) * TILE_US;
    unsigned short* vt = Vimg + (size_t)((((m * 8 + b) * 8 + dc) * 16) + kb) * TILE_US;

    __shared__ unsigned short tile[128 * 132];
    const int t = threadIdx.x;

    #pragma unroll
    for (int i = 0; i < 16; ++i) {
        const int idx = t + i * 256;
        const int r = idx >> 5;
        const int c4 = (idx & 31) << 2;
        const float4 v = *(const float4*)(src + (size_t)r * DIM + c4);
        const unsigned lo = pk2(v.x, v.y), hi2 = pk2(v.z, v.w);
        *(uint2*)(kt + r * 128 + (c4 ^ ((r & 15) << 3))) = make_uint2(lo, hi2);
        *(uint2*)(&tile[r * 132 + c4]) = make_uint2(lo, hi2);
    }
    __syncthreads();
    #pragma unroll
    for (int i = 0; i < 32; ++i) {
        const int widx = t + i * 256;
        const int dcl = widx >> 6;
        const int wk  = widx & 63;
        const unsigned a  = tile[(wk * 2) * 132 + dcl];
        const unsigned bb = tile[(wk * 2 + 1) * 132 + dcl];
        ((unsigned*)vt)[dcl * 64 + (wk ^ ((dcl & 15) << 2))] = a | (bb << 16);
    }
}

// ============ main: R4 order + end-of-phase waits + cross-kb pipelining ============
// phase p: BAR [publishes item p (own-waited last phase), closes readers of slot p+2];
//          issue item p+2; MFMA item p; VMCNT(N) [own item p+1 landed].
__global__ __launch_bounds__(512, 2)
void coattn_main(const float* __restrict__ Sp, const float* __restrict__ Dp,
                 float* __restrict__ outp,
                 const unsigned short* __restrict__ Kimg,
                 const unsigned short* __restrict__ Vimg)
{
    const int s   = blockIdx.x;
    const int g   = (s & 7) | ((s >> 8) << 3);
    const int qb  = (s >> 3) & 31;
    const int dir = g >> 3;
    const int b   = g & 7;
    const int mat_k = dir;
    const int mat_q = 1 - dir;

    const float* Qg = (dir ? Sp : Dp) + (size_t)b * LSEQ * DIM;
    float* Og = outp + (size_t)dir * ((size_t)B_ * LSEQ * DIM) + (size_t)b * LSEQ * DIM;
    const int q0 = qb * QBLK;

    const unsigned short* kbase = Kimg + (size_t)(mat_k * 8 + b) * 16 * 8 * TILE_US;
    const unsigned short* qbase = Kimg + (size_t)(mat_q * 8 + b) * 16 * 8 * TILE_US
                                + (size_t)(qb >> 1) * 8 * TILE_US + (size_t)(qb & 1) * 8192;
    const unsigned short* vbase = Vimg + (size_t)(mat_k * 8 + b) * 8 * 16 * TILE_US;

    __shared__ unsigned short Rr[3][16384];   // 96 KB: K-chunks / V-bands ring
    __shared__ unsigned short QR_[3][8192];   // 48 KB: Q-chunks ring (one slot aliased for P)
    __shared__ float redmax[2][4][32];
    __shared__ float redsum[2][4][32];
    __shared__ float alf[QBLK];

    const int t    = threadIdx.x;
    const int lane = t & 63;
    const int w    = t >> 6;
    const int l31  = lane & 31;
    const int hi   = lane >> 5;
    const int ksub = w & 3;
    const int qh   = w >> 2;

    const int krow = ksub * 32 + l31;
    const int qrow = qh * 32 + l31;
    const int kswz = (krow & 15) << 3;
    const int qswz = (qrow & 15) << 3;
    const int dcl  = ksub * 32 + l31;
    const int vswz = (dcl & 15) << 3;

    f32x16 O[NBAND];
    #pragma unroll
    for (int i = 0; i < NBAND; ++i)
        #pragma unroll
        for (int r = 0; r < 16; ++r) O[i][r] = 0.0f;

    float m_run = -INFINITY, l_run = 0.0f;

    #define QK_MMA(RS, QS)                                                        \
    do {                                                                          \
        const unsigned short* Kb = Rr[RS];                                        \
        const unsigned short* Qb = QR_[QS];                                       \
        __builtin_amdgcn_s_setprio(1);                                            \
        _Pragma("unroll")                                                         \
        for (int kc = 0; kc < 8; ++kc) {                                          \
            const int d0 = kc * 16 + hi * 8;                                      \
            f16x8 a  = *(const f16x8*)&Kb[krow * 128 + (d0 ^ kswz)];              \
            f16x8 bq = *(const f16x8*)&Qb[qrow * 128 + (d0 ^ qswz)];              \
            C = __builtin_amdgcn_mfma_f32_32x32x16_f16(a, bq, C, 0, 0, 0);        \
        }                                                                         \
        __builtin_amdgcn_s_setprio(0);                                            \
    } while (0)

    #define PV_MMA(BAND, RS)                                                      \
    do {                                                                          \
        const unsigned short* Vb = Rr[RS];                                        \
        __builtin_amdgcn_s_setprio(1);                                            \
        _Pragma("unroll")                                                         \
        for (int kc = 0; kc < 8; ++kc) {                                          \
            const int kk0 = kc * 16 + hi * 8;                                     \
            f16x8 vb = *(const f16x8*)&Vb[dcl * 128 + (kk0 ^ vswz)];              \
            O[BAND] = __builtin_amdgcn_mfma_f32_32x32x16_f16(pa[kc], vb, O[BAND], 0, 0, 0); \
        }                                                                         \
        __builtin_amdgcn_s_setprio(0);                                            \
    } while (0)

    // QK phase P (0..5): compute chunk P, issue chunk P+2, end-wait drains P+1
    #define QK_PHASE(P)                                                           \
    do {                                                                          \
        BAR();                                                                    \
        issue32(kt + (P + 2) * TILE_US, Rr[s3(sb + ((P + 2) % 3))], w, lane);     \
        issue16(qbase + (P + 2) * TILE_US, QR_[s3(qsb + ((P + 2) % 3))], w, lane);\
        QK_MMA(s3(sb + (P % 3)), s3(qsb + (P % 3)));                              \
        VMCNT(6);                                                                 \
    } while (0)

    // PV phase for band V (1..5): compute band V, issue V-band V+2, drain V+1
    #define PV_PHASE(V)                                                           \
    do {                                                                          \
        BAR();                                                                    \
        issue32(vbase + (size_t)((V + 2) * 16 + kb) * TILE_US,                    \
                Rr[s3(sb + ((V + 10) % 3))], w, lane);                            \
        PV_MMA(V, s3(sb + ((V + 8) % 3)));                                        \
        VMCNT(4);                                                                 \
    } while (0)

    // prologue: KQ items 0,1 of kb 0 in flight; own item 0 drained (published at
    // the first phase's barrier)
    issue32(kbase + 0 * TILE_US, Rr[0], w, lane);
    issue16(qbase + 0 * TILE_US, QR_[0], w, lane);
    issue32(kbase + 1 * TILE_US, Rr[1], w, lane);
    issue16(qbase + 1 * TILE_US, QR_[1], w, lane);
    VMCNT(6);

    int sb = 0, qsb = 0;   // rotating ring bases: sb=(kb*16)%3, qsb=(kb*8)%3

    #pragma unroll 1
    for (int kb = 0; kb < NKB; ++kb) {
        const unsigned short* kt = kbase + (size_t)kb * 8 * TILE_US;

        f32x16 C;
        #pragma unroll
        for (int r = 0; r < 16; ++r) C[r] = 0.0f;

        // ---- QK phases 0..7 ----
        QK_PHASE(0); QK_PHASE(1); QK_PHASE(2);
        QK_PHASE(3); QK_PHASE(4); QK_PHASE(5);
        // phase 6: issue V0; end-wait drains KQ7 (leaves V0 in flight)
        BAR();
        issue32(vbase + (size_t)(0 * 16 + kb) * TILE_US, Rr[s3(sb + 2)], w, lane);
        QK_MMA(s3(sb + 0), s3(qsb + 0));
        VMCNT(4);
        // phase 7: issue V1; no wait (V0 drained at softmax bar2)
        BAR();
        issue32(vbase + (size_t)(1 * 16 + kb) * TILE_US, Rr[s3(sb + 0)], w, lane);
        QK_MMA(s3(sb + 1), s3(qsb + 1));

        // ---- online softmax (lgkm-only barriers; V0/V1 DMA stays in flight) ----
        unsigned short* Plds = QR_[s3(qsb + 1)];   // dead Q slot until next kb phase 0

        float rm = -INFINITY;
        #pragma unroll
        for (int r = 0; r < 16; ++r) rm = fmaxf(rm, C[r]);
        rm = fmaxf(rm, __shfl_xor(rm, 32));
        if (lane < 32) redmax[qh][ksub][l31] = rm;
        LGKM0(); BAR();

        const float bm = fmaxf(fmaxf(redmax[qh][0][l31], redmax[qh][1][l31]),
                               fmaxf(redmax[qh][2][l31], redmax[qh][3][l31]));
        const float mn = fmaxf(m_run, bm);
        const float al = __expf(m_run - mn);
        float p[16];
        float ps = 0.0f;
        #pragma unroll
        for (int r = 0; r < 16; ++r) { p[r] = __expf(C[r] - mn); ps += p[r]; }
        ps += __shfl_xor(ps, 32);
        if (lane < 32) {
            redsum[qh][ksub][l31] = ps;
            if (ksub == 0) alf[qh * 32 + l31] = al;
        }
        {   // P (fp16) -> LDS [q][k]
            #pragma unroll
            for (int rp = 0; rp < 8; ++rp) {
                const int r  = rp * 2;
                const int kk = ksub * 32 + (r & 3) + 8 * (r >> 2) + 4 * hi;
                *(unsigned*)&Plds[qrow * KBLK + (kk ^ qswz)] = pk2(p[r], p[r + 1]);
            }
        }
        LGKM0(); VMCNT(4); BAR();    // drains V0 (V1 stays); barrier publishes

        const float bs = redsum[qh][0][l31] + redsum[qh][1][l31] +
                         redsum[qh][2][l31] + redsum[qh][3][l31];
        l_run = l_run * al + bs;
        m_run = mn;

        float alr[16];
        #pragma unroll
        for (int r = 0; r < 16; ++r)
            alr[r] = alf[qh * 32 + (r & 3) + 8 * (r >> 2) + 4 * hi];
        #pragma unroll
        for (int i = 0; i < NBAND; ++i)
            #pragma unroll
            for (int r = 0; r < 16; ++r) O[i][r] *= alr[r];

        f16x8 pa[8];
        #pragma unroll
        for (int kc = 0; kc < 8; ++kc) {
            const int kk0 = kc * 16 + hi * 8;
            pa[kc] = *(const f16x8*)&Plds[qrow * KBLK + (kk0 ^ qswz)];
        }

        // ---- PV phases: bands 0..7 ----
        // band 0 (barrier role served by softmax bar2)
        issue32(vbase + (size_t)(2 * 16 + kb) * TILE_US, Rr[s3(sb + 1)], w, lane);
        PV_MMA(0, s3(sb + 2));
        VMCNT(4);
        PV_PHASE(1); PV_PHASE(2); PV_PHASE(3); PV_PHASE(4); PV_PHASE(5);
        // band 6: issue next-kb KQ0; end-wait drains V7
        BAR();
        if (kb + 1 < NKB) {
            const unsigned short* ktn = kbase + (size_t)(kb + 1) * 8 * TILE_US;
            issue32(ktn + 0 * TILE_US, Rr[s3(sb + 1)], w, lane);
            issue16(qbase + 0 * TILE_US, QR_[s3(qsb + 2)], w, lane);
        }
        PV_MMA(6, s3(sb + 2));
        if (kb + 1 < NKB) { VMCNT(6); } else { VMCNT(0); }
        // band 7: issue next-kb KQ1; end-wait drains KQ0'
        BAR();
        if (kb + 1 < NKB) {
            const unsigned short* ktn = kbase + (size_t)(kb + 1) * 8 * TILE_US;
            issue32(ktn + 1 * TILE_US, Rr[s3(sb + 2)], w, lane);
            issue16(qbase + 1 * TILE_US, QR_[qsb], w, lane);
        }
        PV_MMA(7, sb);
        if (kb + 1 < NKB) { VMCNT(6); } else { VMCNT(0); }

        sb = s3(sb + 1);     // (kb+1)*16 % 3
        qsb = s3(qsb + 2);   // (kb+1)*8 % 3
    }

    // ---- epilogue: out = residual(Q) + O / l ----
    __syncthreads();
    if (lane < 32 && ksub == 0) alf[qh * 32 + l31] = 1.0f / l_run;
    __syncthreads();
    #pragma unroll
    for (int r = 0; r < 16; ++r) {
        const int qr = qh * 32 + (r & 3) + 8 * (r >> 2) + 4 * hi;
        const float il = alf[qr];
        const size_t rowoff = (size_t)(q0 + qr) * DIM;
        #pragma unroll
        for (int band = 0; band < NBAND; ++band) {
            const int dcol = band * 128 + ksub * 32 + l31;
            Og[rowoff + dcol] = Qg[rowoff + dcol] + O[band][r] * il;
        }
    }
    #undef QK_MMA
    #undef PV_MMA
    #undef QK_PHASE
    #undef PV_PHASE
}

// ============ fallback (round-2 kernel, verbatim — used if ws too small) ============
#define NDC   8

__global__ __launch_bounds__(512, 2)
void coattn_fb(const float* __restrict__ Sp, const float* __restrict__ Dp,
               float* __restrict__ outp)
{
    const int s   = blockIdx.x;
    const int g   = (s & 7) | ((s >> 8) << 3);
    const int qb  = (s >> 3) & 31;
    const int dir = g >> 3;
    const int b   = g & 7;

    const float* Qg = (dir ? Sp : Dp) + (size_t)b * LSEQ * DIM;
    const float* Kg = (dir ? Dp : Sp) + (size_t)b * LSEQ * DIM;
    float* Og = outp + (size_t)dir * ((size_t)B_ * LSEQ * DIM) + (size_t)b * LSEQ * DIM;
    const int q0 = qb * QBLK;

    __shared__ unsigned short Klds[KBLK * 128];
    __shared__ unsigned short Qlds[QBLK * 128];
    __shared__ unsigned short Plds[QBLK * KBLK];
    __shared__ unsigned short Vlds[128 * KBLK];
    __shared__ float redmax[2][4][32];
    __shared__ float redsum[2][4][32];
    __shared__ float alf[QBLK];

    const int t    = threadIdx.x;
    const int lane = t & 63;
    const int w    = t >> 6;
    const int l31  = lane & 31;
    const int hi   = lane >> 5;
    const int ksub = w & 3;
    const int qh   = w >> 2;

    f32x16 O[NBAND];
    #pragma unroll
    for (int i = 0; i < NBAND; ++i)
        #pragma unroll
        for (int r = 0; r < 16; ++r) O[i][r] = 0.0f;

    float m_run = -INFINITY, l_run = 0.0f;

    const int srow = t >> 4;
    const int fcol = (t & 15) << 2;
    const int vmm  = t & 31;
    const int vkp0 = t >> 5;

    const int krow = ksub * 32 + l31;
    const int qrow = qh * 32 + l31;

    for (int kb = 0; kb < NKB; ++kb) {
        const int k0g = kb * KBLK;
        f32x16 C;
        #pragma unroll
        for (int r = 0; r < 16; ++r) C[r] = 0.0f;

        float4 kreg[8], qreg[4];
        #pragma unroll
        for (int pass = 0; pass < 4; ++pass)
            #pragma unroll
            for (int h = 0; h < 2; ++h)
                kreg[pass * 2 + h] = *(const float4*)(Kg + (size_t)(k0g + pass * 32 + srow) * DIM + fcol + h * 64);
        #pragma unroll
        for (int pass = 0; pass < 2; ++pass)
            #pragma unroll
            for (int h = 0; h < 2; ++h)
                qreg[pass * 2 + h] = *(const float4*)(Qg + (size_t)(q0 + pass * 32 + srow) * DIM + fcol + h * 64);

        #pragma unroll 1
        for (int dc = 0; dc < NDC; ++dc) {
            __syncthreads();
            #pragma unroll
            for (int pass = 0; pass < 4; ++pass)
                #pragma unroll
                for (int h = 0; h < 2; ++h) {
                    const int row = pass * 32 + srow;
                    const int d   = fcol + h * 64;
                    const float4 v = kreg[pass * 2 + h];
                    *(uint2*)&Klds[row * 128 + (d ^ ((row & 7) << 3))] =
                        make_uint2(pk2(v.x, v.y), pk2(v.z, v.w));
                }
            #pragma unroll
            for (int pass = 0; pass < 2; ++pass)
                #pragma unroll
                for (int h = 0; h < 2; ++h) {
                    const int row = pass * 32 + srow;
                    const int d   = fcol + h * 64;
                    const float4 v = qreg[pass * 2 + h];
                    *(uint2*)&Qlds[row * 128 + (d ^ ((row & 7) << 3))] =
                        make_uint2(pk2(v.x, v.y), pk2(v.z, v.w));
                }
            __syncthreads();
            if (dc + 1 < NDC) {
                const int dbase = (dc + 1) * 128;
                #pragma unroll
                for (int pass = 0; pass < 4; ++pass)
                    #pragma unroll
                    for (int h = 0; h < 2; ++h)
                        kreg[pass * 2 + h] = *(const float4*)(Kg + (size_t)(k0g + pass * 32 + srow) * DIM + dbase + fcol + h * 64);
                #pragma unroll
                for (int pass = 0; pass < 2; ++pass)
                    #pragma unroll
                    for (int h = 0; h < 2; ++h)
                        qreg[pass * 2 + h] = *(const float4*)(Qg + (size_t)(q0 + pass * 32 + srow) * DIM + dbase + fcol + h * 64);
            }
            #pragma unroll
            for (int kc = 0; kc < 8; ++kc) {
                const int d0 = kc * 16 + hi * 8;
                f16x8 a  = *(const f16x8*)&Klds[krow * 128 + (d0 ^ ((krow & 7) << 3))];
                f16x8 bq = *(const f16x8*)&Qlds[qrow * 128 + (d0 ^ ((qrow & 7) << 3))];
                C = __builtin_amdgcn_mfma_f32_32x32x16_f16(a, bq, C, 0, 0, 0);
            }
        }

        float rm = -INFINITY;
        #pragma unroll
        for (int r = 0; r < 16; ++r) rm = fmaxf(rm, C[r]);
        rm = fmaxf(rm, __shfl_xor(rm, 32));
        if (lane < 32) redmax[qh][ksub][l31] = rm;
        __syncthreads();

        const float bm = fmaxf(fmaxf(redmax[qh][0][l31], redmax[qh][1][l31]),
                               fmaxf(redmax[qh][2][l31], redmax[qh][3][l31]));
        const float mn = fmaxf(m_run, bm);
        const float al = __expf(m_run - mn);
        float p[16];
        float ps = 0.0f;
        #pragma unroll
        for (int r = 0; r < 16; ++r) { p[r] = __expf(C[r] - mn); ps += p[r]; }
        ps += __shfl_xor(ps, 32);
        if (lane < 32) {
            redsum[qh][ksub][l31] = ps;
            if (ksub == 0) alf[qh * 32 + l31] = al;
        }
        {
            #pragma unroll
            for (int rp = 0; rp < 8; ++rp) {
                const int r  = rp * 2;
                const int kk = ksub * 32 + (r & 3) + 8 * (r >> 2) + 4 * hi;
                *(unsigned*)&Plds[qrow * KBLK + (kk ^ ((qrow & 7) << 3))] = pk2(p[r], p[r + 1]);
            }
        }
        __syncthreads();

        const float bs = redsum[qh][0][l31] + redsum[qh][1][l31] +
                         redsum[qh][2][l31] + redsum[qh][3][l31];
        l_run = l_run * al + bs;
        m_run = mn;

        float alr[16];
        #pragma unroll
        for (int r = 0; r < 16; ++r)
            alr[r] = alf[qh * 32 + (r & 3) + 8 * (r >> 2) + 4 * hi];
        #pragma unroll
        for (int i = 0; i < NBAND; ++i)
            #pragma unroll
            for (int r = 0; r < 16; ++r) O[i][r] *= alr[r];

        f16x8 pa[8];
        #pragma unroll
        for (int kc = 0; kc < 8; ++kc) {
            const int kk0 = kc * 16 + hi * 8;
            pa[kc] = *(const f16x8*)&Plds[qrow * KBLK + (kk0 ^ ((qrow & 7) << 3))];
        }

        float4 v0s[4], v1s[4];
        #pragma unroll
        for (int pass = 0; pass < 4; ++pass) {
            const int kp = pass * 16 + vkp0;
            v0s[pass] = *(const float4*)(Kg + (size_t)(k0g + 2 * kp) * DIM + vmm * 4);
            v1s[pass] = *(const float4*)(Kg + (size_t)(k0g + 2 * kp + 1) * DIM + vmm * 4);
        }

        #pragma unroll
        for (int band = 0; band < NBAND; ++band) {
            __syncthreads();
            #pragma unroll
            for (int pass = 0; pass < 4; ++pass) {
                const int kp = pass * 16 + vkp0;
                const float* a0 = (const float*)&v0s[pass];
                const float* a1 = (const float*)&v1s[pass];
                #pragma unroll
                for (int j = 0; j < 4; ++j) {
                    const int dclw = vmm * 4 + j;
                    *(unsigned*)&Vlds[dclw * KBLK + ((2 * kp) ^ ((dclw & 7) << 3))] = pk2(a0[j], a1[j]);
                }
            }
            __syncthreads();
            if (band + 1 < NBAND) {
                const int cb = (band + 1) * 128;
                #pragma unroll
                for (int pass = 0; pass < 4; ++pass) {
                    const int kp = pass * 16 + vkp0;
                    v0s[pass] = *(const float4*)(Kg + (size_t)(k0g + 2 * kp) * DIM + cb + vmm * 4);
                    v1s[pass] = *(const float4*)(Kg + (size_t)(k0g + 2 * kp + 1) * DIM + cb + vmm * 4);
                }
            }
            const int dclr = ksub * 32 + l31;
            const int sw  = (dclr & 7) << 3;
            #pragma unroll
            for (int kc = 0; kc < 8; ++kc) {
                const int kk0 = kc * 16 + hi * 8;
                f16x8 vb = *(const f16x8*)&Vlds[dclr * KBLK + (kk0 ^ sw)];
                O[band] = __builtin_amdgcn_mfma_f32_32x32x16_f16(pa[kc], vb, O[band], 0, 0, 0);
            }
        }
    }

    if (lane < 32 && ksub == 0) alf[qh * 32 + l31] = 1.0f / l_run;
    __syncthreads();
    #pragma unroll
    for (int r = 0; r < 16; ++r) {
        const int qr = qh * 32 + (r & 3) + 8 * (r >> 2) + 4 * hi;
        const float il = alf[qr];
        const size_t rowoff = (size_t)(q0 + qr) * DIM;
        #pragma unroll
        for (int band = 0; band < NBAND; ++band) {
            const int dcol = band * 128 + ksub * 32 + l31;
            Og[rowoff + dcol] = Qg[rowoff + dcol] + O[band][r] * il;
        }
    }
}

extern "C" void kernel_launch(void* const* d_in, const int* in_sizes, int n_in,
                              void* d_out, int out_size, void* d_ws, size_t ws_size,
                              hipStream_t stream) {
    const float* S = (const float*)d_in[0];
    const float* D = (const float*)d_in[1];
    float* out = (float*)d_out;
    if (ws_size >= WS_NEED) {
        unsigned short* Kimg = (unsigned short*)d_ws;
        unsigned short* Vimg = Kimg + KIMG_US;
        prepass<<<dim3(2048, 1, 1), dim3(256, 1, 1), 0, stream>>>(S, D, Kimg, Vimg);
        coattn_main<<<dim3(512, 1, 1), dim3(512, 1, 1), 0, stream>>>(S, D, out, Kimg, Vimg);
    } else {
        coattn_fb<<<dim3(512, 1, 1), dim3(512, 1, 1), 0, stream>>>(S, D, out);
    }
}

// Round 10
// 624.211 us; speedup vs baseline: 2.3950x; 1.3293x over previous
//
#include <hip/hip_runtime.h>

typedef __attribute__((ext_vector_type(8))) _Float16 f16x8;
typedef __attribute__((ext_vector_type(16))) float f32x16;

#define B_    8
#define LSEQ  2048
#define DIM   1024
#define QBLK  64
#define KBLK  128
#define NKB   (LSEQ / KBLK)   // 16
#define NBAND 8

// K/V image geometry: 32KB tiles (128x128 fp16, 4-bit row-XOR swizzle baked in)
#define TILE_US   16384        // ushorts per tile
#define KIMG_US   ((size_t)2 * 8 * 16 * 8 * TILE_US)   // 64 MB
#define WS_NEED   ((size_t)2 * KIMG_US * 2)            // 128 MB

static __device__ __forceinline__ unsigned pk2(float a, float b) {
    return __builtin_bit_cast(unsigned, __builtin_amdgcn_cvt_pkrtz(a, b));
}

#define VMCNT(n) asm volatile("s_waitcnt vmcnt(" #n ")" ::: "memory")
#define LGKM0()  asm volatile("s_waitcnt lgkmcnt(0)" ::: "memory")
#define BAR()    do { asm volatile("" ::: "memory"); __builtin_amdgcn_s_barrier(); \
                      asm volatile("" ::: "memory"); } while (0)

static __device__ __forceinline__ int s3(int x) { return x >= 3 ? x - 3 : x; }

static __device__ __forceinline__ void gll16(const void* g, void* l) {
    __builtin_amdgcn_global_load_lds(
        (const __attribute__((address_space(1))) void*)g,
        (__attribute__((address_space(3))) void*)l, 16, 0, 0);
}

// 32KB tile: 8 waves x 4 ops x 1KB ; 16KB tile: 8 waves x 2 ops x 1KB
static __device__ __forceinline__ void issue32(const unsigned short* gt, unsigned short* lb, int w, int lane) {
    #pragma unroll
    for (int j = 0; j < 4; ++j) {
        const int off = (w * 4 + j) * 1024;
        gll16((const char*)gt + off + lane * 16, (char*)lb + off);
    }
}
static __device__ __forceinline__ void issue16(const unsigned short* gt, unsigned short* lb, int w, int lane) {
    #pragma unroll
    for (int j = 0; j < 2; ++j) {
        const int off = (w * 2 + j) * 1024;
        gll16((const char*)gt + off + lane * 16, (char*)lb + off);
    }
}

// ============ prepass: fp32 -> fp16 swizzled LDS-image tiles (4-bit row XOR) ============
__global__ __launch_bounds__(256)
void prepass(const float* __restrict__ Sp, const float* __restrict__ Dp,
             unsigned short* __restrict__ Kimg, unsigned short* __restrict__ Vimg)
{
    const int blk = blockIdx.x;            // 2*8*16*8 = 2048
    const int dc = blk & 7;
    const int kb = (blk >> 3) & 15;
    const int b  = (blk >> 7) & 7;
    const int m  = blk >> 10;
    const float* src = (m ? Dp : Sp) + ((size_t)b * LSEQ + kb * 128) * DIM + dc * 128;
    unsigned short* kt = Kimg + (size_t)((((m * 8 + b) * 16 + kb) * 8) + dc) * TILE_US;
    unsigned short* vt = Vimg + (size_t)((((m * 8 + b) * 8 + dc) * 16) + kb) * TILE_US;

    __shared__ unsigned short tile[128 * 132];
    const int t = threadIdx.x;

    #pragma unroll
    for (int i = 0; i < 16; ++i) {
        const int idx = t + i * 256;
        const int r = idx >> 5;
        const int c4 = (idx & 31) << 2;
        const float4 v = *(const float4*)(src + (size_t)r * DIM + c4);
        const unsigned lo = pk2(v.x, v.y), hi2 = pk2(v.z, v.w);
        *(uint2*)(kt + r * 128 + (c4 ^ ((r & 15) << 3))) = make_uint2(lo, hi2);
        *(uint2*)(&tile[r * 132 + c4]) = make_uint2(lo, hi2);
    }
    __syncthreads();
    #pragma unroll
    for (int i = 0; i < 32; ++i) {
        const int widx = t + i * 256;
        const int dcl = widx >> 6;
        const int wk  = widx & 63;
        const unsigned a  = tile[(wk * 2) * 132 + dcl];
        const unsigned bb = tile[(wk * 2 + 1) * 132 + dcl];
        ((unsigned*)vt)[dcl * 64 + (wk ^ ((dcl & 15) << 2))] = a | (bb << 16);
    }
}

// ============ main: R4 16-phase ring pipeline, verbatim protocol ============
__global__ __launch_bounds__(512, 2)
void coattn_main(const float* __restrict__ Sp, const float* __restrict__ Dp,
                 float* __restrict__ outp,
                 const unsigned short* __restrict__ Kimg,
                 const unsigned short* __restrict__ Vimg)
{
    const int s   = blockIdx.x;
    const int g   = (s & 7) | ((s >> 8) << 3);
    const int qb  = (s >> 3) & 31;
    const int dir = g >> 3;
    const int b   = g & 7;
    const int mat_k = dir;
    const int mat_q = 1 - dir;

    const float* Qg = (dir ? Sp : Dp) + (size_t)b * LSEQ * DIM;
    float* Og = outp + (size_t)dir * ((size_t)B_ * LSEQ * DIM) + (size_t)b * LSEQ * DIM;
    const int q0 = qb * QBLK;

    const unsigned short* kbase = Kimg + (size_t)(mat_k * 8 + b) * 16 * 8 * TILE_US;
    const unsigned short* qbase = Kimg + (size_t)(mat_q * 8 + b) * 16 * 8 * TILE_US
                                + (size_t)(qb >> 1) * 8 * TILE_US + (size_t)(qb & 1) * 8192;
    const unsigned short* vbase = Vimg + (size_t)(mat_k * 8 + b) * 8 * 16 * TILE_US;

    __shared__ unsigned short Rr[3][16384];   // 96 KB: K-chunks / V-bands ring
    __shared__ unsigned short QR_[3][8192];   // 48 KB: Q-chunks ring (slot0 reused for P)
    __shared__ float redmax[2][4][32];
    __shared__ float redsum[2][4][32];
    __shared__ float alf[QBLK];

    const int t    = threadIdx.x;
    const int lane = t & 63;
    const int w    = t >> 6;
    const int l31  = lane & 31;
    const int hi   = lane >> 5;
    const int ksub = w & 3;
    const int qh   = w >> 2;

    const int krow = ksub * 32 + l31;
    const int qrow = qh * 32 + l31;
    const int kswz = (krow & 15) << 3;
    const int qswz = (qrow & 15) << 3;
    const int dcl  = ksub * 32 + l31;
    const int vswz = (dcl & 15) << 3;

    unsigned short* Plds = QR_[0];

    f32x16 O[NBAND];
    #pragma unroll
    for (int i = 0; i < NBAND; ++i)
        #pragma unroll
        for (int r = 0; r < 16; ++r) O[i][r] = 0.0f;

    float m_run = -INFINITY, l_run = 0.0f;

    #define QK_MMA(SLOT)                                                          \
    do {                                                                          \
        const unsigned short* Kb = Rr[SLOT];                                      \
        const unsigned short* Qb = QR_[SLOT];                                     \
        __builtin_amdgcn_s_setprio(1);                                            \
        _Pragma("unroll")                                                         \
        for (int kc = 0; kc < 8; ++kc) {                                          \
            const int d0 = kc * 16 + hi * 8;                                      \
            f16x8 a  = *(const f16x8*)&Kb[krow * 128 + (d0 ^ kswz)];              \
            f16x8 bq = *(const f16x8*)&Qb[qrow * 128 + (d0 ^ qswz)];              \
            C = __builtin_amdgcn_mfma_f32_32x32x16_f16(a, bq, C, 0, 0, 0);        \
        }                                                                         \
        __builtin_amdgcn_s_setprio(0);                                            \
    } while (0)

    #define PV_MMA(BAND, SLOT)                                                    \
    do {                                                                          \
        const unsigned short* Vb = Rr[SLOT];                                      \
        __builtin_amdgcn_s_setprio(1);                                            \
        _Pragma("unroll")                                                         \
        for (int kc = 0; kc < 8; ++kc) {                                          \
            const int kk0 = kc * 16 + hi * 8;                                     \
            f16x8 vb = *(const f16x8*)&Vb[dcl * 128 + (kk0 ^ vswz)];              \
            O[BAND] = __builtin_amdgcn_mfma_f32_32x32x16_f16(pa[kc], vb, O[BAND], 0, 0, 0); \
        }                                                                         \
        __builtin_amdgcn_s_setprio(0);                                            \
    } while (0)

    #pragma unroll 1
    for (int kb = 0; kb < NKB; ++kb) {
        const unsigned short* kt = kbase + (size_t)kb * 8 * TILE_US;

        f32x16 C;
        #pragma unroll
        for (int r = 0; r < 16; ++r) C[r] = 0.0f;

        // ---- prologue: chunks 0,1 in flight; chunk0 verified ----
        BAR();                                       // closes prev kb's phase-15 reads
        issue32(kt + 0 * TILE_US, Rr[0], w, lane);
        issue16(qbase + 0 * TILE_US, QR_[0], w, lane);
        issue32(kt + 1 * TILE_US, Rr[1], w, lane);
        issue16(qbase + 1 * TILE_US, QR_[1], w, lane);
        VMCNT(6);                                    // own chunk0 landed
        BAR();                                       // all waves' chunk0 landed

        // ---- QK phases 0..7 (compute chunk p from slot p%3) ----
        issue32(kt + 2 * TILE_US, Rr[2], w, lane);   // phase 0
        issue16(qbase + 2 * TILE_US, QR_[2], w, lane);
        VMCNT(6);
        QK_MMA(0);

        BAR();                                       // phase 1
        issue32(kt + 3 * TILE_US, Rr[0], w, lane);
        issue16(qbase + 3 * TILE_US, QR_[0], w, lane);
        VMCNT(6);
        QK_MMA(1);

        BAR();                                       // phase 2
        issue32(kt + 4 * TILE_US, Rr[1], w, lane);
        issue16(qbase + 4 * TILE_US, QR_[1], w, lane);
        VMCNT(6);
        QK_MMA(2);

        BAR();                                       // phase 3
        issue32(kt + 5 * TILE_US, Rr[2], w, lane);
        issue16(qbase + 5 * TILE_US, QR_[2], w, lane);
        VMCNT(6);
        QK_MMA(0);

        BAR();                                       // phase 4
        issue32(kt + 6 * TILE_US, Rr[0], w, lane);
        issue16(qbase + 6 * TILE_US, QR_[0], w, lane);
        VMCNT(6);
        QK_MMA(1);

        BAR();                                       // phase 5
        issue32(kt + 7 * TILE_US, Rr[1], w, lane);
        issue16(qbase + 7 * TILE_US, QR_[1], w, lane);
        VMCNT(6);
        QK_MMA(2);

        BAR();                                       // phase 6: V0 prefetch starts
        issue32(vbase + (size_t)(0 * 16 + kb) * TILE_US, Rr[2], w, lane);
        VMCNT(4);                                    // chunk7 landed
        QK_MMA(0);

        BAR();                                       // phase 7
        issue32(vbase + (size_t)(1 * 16 + kb) * TILE_US, Rr[0], w, lane);
        VMCNT(4);                                    // V0 landed
        QK_MMA(1);

        // ---- online softmax (kept on __syncthreads; drains are ~1-phase-old V DMA) ----
        float rm = -INFINITY;
        #pragma unroll
        for (int r = 0; r < 16; ++r) rm = fmaxf(rm, C[r]);
        rm = fmaxf(rm, __shfl_xor(rm, 32));
        if (lane < 32) redmax[qh][ksub][l31] = rm;
        __syncthreads();

        const float bm = fmaxf(fmaxf(redmax[qh][0][l31], redmax[qh][1][l31]),
                               fmaxf(redmax[qh][2][l31], redmax[qh][3][l31]));
        const float mn = fmaxf(m_run, bm);
        const float al = __expf(m_run - mn);
        float p[16];
        float ps = 0.0f;
        #pragma unroll
        for (int r = 0; r < 16; ++r) { p[r] = __expf(C[r] - mn); ps += p[r]; }
        ps += __shfl_xor(ps, 32);
        if (lane < 32) {
            redsum[qh][ksub][l31] = ps;
            if (ksub == 0) alf[qh * 32 + l31] = al;
        }
        {   // P (fp16) -> LDS [q][k] (Plds aliases QR_[0]; Q chunk6 dead since phase 6)
            #pragma unroll
            for (int rp = 0; rp < 8; ++rp) {
                const int r  = rp * 2;
                const int kk = ksub * 32 + (r & 3) + 8 * (r >> 2) + 4 * hi;
                *(unsigned*)&Plds[qrow * KBLK + (kk ^ qswz)] = pk2(p[r], p[r + 1]);
            }
        }
        __syncthreads();

        const float bs = redsum[qh][0][l31] + redsum[qh][1][l31] +
                         redsum[qh][2][l31] + redsum[qh][3][l31];
        l_run = l_run * al + bs;
        m_run = mn;

        float alr[16];
        #pragma unroll
        for (int r = 0; r < 16; ++r)
            alr[r] = alf[qh * 32 + (r & 3) + 8 * (r >> 2) + 4 * hi];
        #pragma unroll
        for (int i = 0; i < NBAND; ++i)
            #pragma unroll
            for (int r = 0; r < 16; ++r) O[i][r] *= alr[r];

        f16x8 pa[8];
        #pragma unroll
        for (int kc = 0; kc < 8; ++kc) {
            const int kk0 = kc * 16 + hi * 8;
            pa[kc] = *(const f16x8*)&Plds[qrow * KBLK + (kk0 ^ qswz)];
        }

        // ---- PV phases 8..15 (band b from slot (8+b)%3) ----
        issue32(vbase + (size_t)(2 * 16 + kb) * TILE_US, Rr[1], w, lane);  // phase 8
        VMCNT(4);
        PV_MMA(0, 2);

        BAR();                                       // phase 9
        issue32(vbase + (size_t)(3 * 16 + kb) * TILE_US, Rr[2], w, lane);
        VMCNT(4);
        PV_MMA(1, 0);

        BAR();                                       // phase 10
        issue32(vbase + (size_t)(4 * 16 + kb) * TILE_US, Rr[0], w, lane);
        VMCNT(4);
        PV_MMA(2, 1);

        BAR();                                       // phase 11
        issue32(vbase + (size_t)(5 * 16 + kb) * TILE_US, Rr[1], w, lane);
        VMCNT(4);
        PV_MMA(3, 2);

        BAR();                                       // phase 12
        issue32(vbase + (size_t)(6 * 16 + kb) * TILE_US, Rr[2], w, lane);
        VMCNT(4);
        PV_MMA(4, 0);

        BAR();                                       // phase 13
        issue32(vbase + (size_t)(7 * 16 + kb) * TILE_US, Rr[0], w, lane);
        VMCNT(4);
        PV_MMA(5, 1);

        BAR();                                       // phase 14 (no issue)
        PV_MMA(6, 2);

        BAR();                                       // phase 15
        VMCNT(0);                                    // V7 landed (issued 2 phases ago)
        PV_MMA(7, 0);
    }

    // ---- epilogue: out = residual(Q) + O / l ----
    __syncthreads();
    if (lane < 32 && ksub == 0) alf[qh * 32 + l31] = 1.0f / l_run;
    __syncthreads();
    #pragma unroll
    for (int r = 0; r < 16; ++r) {
        const int qr = qh * 32 + (r & 3) + 8 * (r >> 2) + 4 * hi;
        const float il = alf[qr];
        const size_t rowoff = (size_t)(q0 + qr) * DIM;
        #pragma unroll
        for (int band = 0; band < NBAND; ++band) {
            const int dcol = band * 128 + ksub * 32 + l31;
            Og[rowoff + dcol] = Qg[rowoff + dcol] + O[band][r] * il;
        }
    }
    #undef QK_MMA
    #undef PV_MMA
}

// ============ fallback (round-2 kernel, verbatim — used if ws too small) ============
#define NDC   8

__global__ __launch_bounds__(512, 2)
void coattn_fb(const float* __restrict__ Sp, const float* __restrict__ Dp,
               float* __restrict__ outp)
{
    const int s   = blockIdx.x;
    const int g   = (s & 7) | ((s >> 8) << 3);
    const int qb  = (s >> 3) & 31;
    const int dir = g >> 3;
    const int b   = g & 7;

    const float* Qg = (dir ? Sp : Dp) + (size_t)b * LSEQ * DIM;
    const float* Kg = (dir ? Dp : Sp) + (size_t)b * LSEQ * DIM;
    float* Og = outp + (size_t)dir * ((size_t)B_ * LSEQ * DIM) + (size_t)b * LSEQ * DIM;
    const int q0 = qb * QBLK;

    __shared__ unsigned short Klds[KBLK * 128];
    __shared__ unsigned short Qlds[QBLK * 128];
    __shared__ unsigned short Plds[QBLK * KBLK];
    __shared__ unsigned short Vlds[128 * KBLK];
    __shared__ float redmax[2][4][32];
    __shared__ float redsum[2][4][32];
    __shared__ float alf[QBLK];

    const int t    = threadIdx.x;
    const int lane = t & 63;
    const int w    = t >> 6;
    const int l31  = lane & 31;
    const int hi   = lane >> 5;
    const int ksub = w & 3;
    const int qh   = w >> 2;

    f32x16 O[NBAND];
    #pragma unroll
    for (int i = 0; i < NBAND; ++i)
        #pragma unroll
        for (int r = 0; r < 16; ++r) O[i][r] = 0.0f;

    float m_run = -INFINITY, l_run = 0.0f;

    const int srow = t >> 4;
    const int fcol = (t & 15) << 2;
    const int vmm  = t & 31;
    const int vkp0 = t >> 5;

    const int krow = ksub * 32 + l31;
    const int qrow = qh * 32 + l31;

    for (int kb = 0; kb < NKB; ++kb) {
        const int k0g = kb * KBLK;
        f32x16 C;
        #pragma unroll
        for (int r = 0; r < 16; ++r) C[r] = 0.0f;

        float4 kreg[8], qreg[4];
        #pragma unroll
        for (int pass = 0; pass < 4; ++pass)
            #pragma unroll
            for (int h = 0; h < 2; ++h)
                kreg[pass * 2 + h] = *(const float4*)(Kg + (size_t)(k0g + pass * 32 + srow) * DIM + fcol + h * 64);
        #pragma unroll
        for (int pass = 0; pass < 2; ++pass)
            #pragma unroll
            for (int h = 0; h < 2; ++h)
                qreg[pass * 2 + h] = *(const float4*)(Qg + (size_t)(q0 + pass * 32 + srow) * DIM + fcol + h * 64);

        #pragma unroll 1
        for (int dc = 0; dc < NDC; ++dc) {
            __syncthreads();
            #pragma unroll
            for (int pass = 0; pass < 4; ++pass)
                #pragma unroll
                for (int h = 0; h < 2; ++h) {
                    const int row = pass * 32 + srow;
                    const int d   = fcol + h * 64;
                    const float4 v = kreg[pass * 2 + h];
                    *(uint2*)&Klds[row * 128 + (d ^ ((row & 7) << 3))] =
                        make_uint2(pk2(v.x, v.y), pk2(v.z, v.w));
                }
            #pragma unroll
            for (int pass = 0; pass < 2; ++pass)
                #pragma unroll
                for (int h = 0; h < 2; ++h) {
                    const int row = pass * 32 + srow;
                    const int d   = fcol + h * 64;
                    const float4 v = qreg[pass * 2 + h];
                    *(uint2*)&Qlds[row * 128 + (d ^ ((row & 7) << 3))] =
                        make_uint2(pk2(v.x, v.y), pk2(v.z, v.w));
                }
            __syncthreads();
            if (dc + 1 < NDC) {
                const int dbase = (dc + 1) * 128;
                #pragma unroll
                for (int pass = 0; pass < 4; ++pass)
                    #pragma unroll
                    for (int h = 0; h < 2; ++h)
                        kreg[pass * 2 + h] = *(const float4*)(Kg + (size_t)(k0g + pass * 32 + srow) * DIM + dbase + fcol + h * 64);
                #pragma unroll
                for (int pass = 0; pass < 2; ++pass)
                    #pragma unroll
                    for (int h = 0; h < 2; ++h)
                        qreg[pass * 2 + h] = *(const float4*)(Qg + (size_t)(q0 + pass * 32 + srow) * DIM + dbase + fcol + h * 64);
            }
            #pragma unroll
            for (int kc = 0; kc < 8; ++kc) {
                const int d0 = kc * 16 + hi * 8;
                f16x8 a  = *(const f16x8*)&Klds[krow * 128 + (d0 ^ ((krow & 7) << 3))];
                f16x8 bq = *(const f16x8*)&Qlds[qrow * 128 + (d0 ^ ((qrow & 7) << 3))];
                C = __builtin_amdgcn_mfma_f32_32x32x16_f16(a, bq, C, 0, 0, 0);
            }
        }

        float rm = -INFINITY;
        #pragma unroll
        for (int r = 0; r < 16; ++r) rm = fmaxf(rm, C[r]);
        rm = fmaxf(rm, __shfl_xor(rm, 32));
        if (lane < 32) redmax[qh][ksub][l31] = rm;
        __syncthreads();

        const float bm = fmaxf(fmaxf(redmax[qh][0][l31], redmax[qh][1][l31]),
                               fmaxf(redmax[qh][2][l31], redmax[qh][3][l31]));
        const float mn = fmaxf(m_run, bm);
        const float al = __expf(m_run - mn);
        float p[16];
        float ps = 0.0f;
        #pragma unroll
        for (int r = 0; r < 16; ++r) { p[r] = __expf(C[r] - mn); ps += p[r]; }
        ps += __shfl_xor(ps, 32);
        if (lane < 32) {
            redsum[qh][ksub][l31] = ps;
            if (ksub == 0) alf[qh * 32 + l31] = al;
        }
        {
            #pragma unroll
            for (int rp = 0; rp < 8; ++rp) {
                const int r  = rp * 2;
                const int kk = ksub * 32 + (r & 3) + 8 * (r >> 2) + 4 * hi;
                *(unsigned*)&Plds[qrow * KBLK + (kk ^ ((qrow & 7) << 3))] = pk2(p[r], p[r + 1]);
            }
        }
        __syncthreads();

        const float bs = redsum[qh][0][l31] + redsum[qh][1][l31] +
                         redsum[qh][2][l31] + redsum[qh][3][l31];
        l_run = l_run * al + bs;
        m_run = mn;

        float alr[16];
        #pragma unroll
        for (int r = 0; r < 16; ++r)
            alr[r] = alf[qh * 32 + (r & 3) + 8 * (r >> 2) + 4 * hi];
        #pragma unroll
        for (int i = 0; i < NBAND; ++i)
            #pragma unroll
            for (int r = 0; r < 16; ++r) O[i][r] *= alr[r];

        f16x8 pa[8];
        #pragma unroll
        for (int kc = 0; kc < 8; ++kc) {
            const int kk0 = kc * 16 + hi * 8;
            pa[kc] = *(const f16x8*)&Plds[qrow * KBLK + (kk0 ^ ((qrow & 7) << 3))];
        }

        float4 v0s[4], v1s[4];
        #pragma unroll
        for (int pass = 0; pass < 4; ++pass) {
            const int kp = pass * 16 + vkp0;
            v0s[pass] = *(const float4*)(Kg + (size_t)(k0g + 2 * kp) * DIM + vmm * 4);
            v1s[pass] = *(const float4*)(Kg + (size_t)(k0g + 2 * kp + 1) * DIM + vmm * 4);
        }

        #pragma unroll
        for (int band = 0; band < NBAND; ++band) {
            __syncthreads();
            #pragma unroll
            for (int pass = 0; pass < 4; ++pass) {
                const int kp = pass * 16 + vkp0;
                const float* a0 = (const float*)&v0s[pass];
                const float* a1 = (const float*)&v1s[pass];
                #pragma unroll
                for (int j = 0; j < 4; ++j) {
                    const int dclw = vmm * 4 + j;
                    *(unsigned*)&Vlds[dclw * KBLK + ((2 * kp) ^ ((dclw & 7) << 3))] = pk2(a0[j], a1[j]);
                }
            }
            __syncthreads();
            if (band + 1 < NBAND) {
                const int cb = (band + 1) * 128;
                #pragma unroll
                for (int pass = 0; pass < 4; ++pass) {
                    const int kp = pass * 16 + vkp0;
                    v0s[pass] = *(const float4*)(Kg + (size_t)(k0g + 2 * kp) * DIM + cb + vmm * 4);
                    v1s[pass] = *(const float4*)(Kg + (size_t)(k0g + 2 * kp + 1) * DIM + cb + vmm * 4);
                }
            }
            const int dclr = ksub * 32 + l31;
            const int sw  = (dclr & 7) << 3;
            #pragma unroll
            for (int kc = 0; kc < 8; ++kc) {
                const int kk0 = kc * 16 + hi * 8;
                f16x8 vb = *(const f16x8*)&Vlds[dclr * KBLK + (kk0 ^ sw)];
                O[band] = __builtin_amdgcn_mfma_f32_32x32x16_f16(pa[kc], vb, O[band], 0, 0, 0);
            }
        }
    }

    if (lane < 32 && ksub == 0) alf[qh * 32 + l31] = 1.0f / l_run;
    __syncthreads();
    #pragma unroll
    for (int r = 0; r < 16; ++r) {
        const int qr = qh * 32 + (r & 3) + 8 * (r >> 2) + 4 * hi;
        const float il = alf[qr];
        const size_t rowoff = (size_t)(q0 + qr) * DIM;
        #pragma unroll
        for (int band = 0; band < NBAND; ++band) {
            const int dcol = band * 128 + ksub * 32 + l31;
            Og[rowoff + dcol] = Qg[rowoff + dcol] + O[band][r] * il;
        }
    }
}

extern "C" void kernel_launch(void* const* d_in, const int* in_sizes, int n_in,
                              void* d_out, int out_size, void* d_ws, size_t ws_size,
                              hipStream_t stream) {
    const float* S = (const float*)d_in[0];
    const float* D = (const float*)d_in[1];
    float* out = (float*)d_out;
    if (ws_size >= WS_NEED) {
        unsigned short* Kimg = (unsigned short*)d_ws;
        unsigned short* Vimg = Kimg + KIMG_US;
        prepass<<<dim3(2048, 1, 1), dim3(256, 1, 1), 0, stream>>>(S, D, Kimg, Vimg);
        coattn_main<<<dim3(512, 1, 1), dim3(512, 1, 1), 0, stream>>>(S, D, out, Kimg, Vimg);
    } else {
        coattn_fb<<<dim3(512, 1, 1), dim3(512, 1, 1), 0, stream>>>(S, D, out);
    }
}